// Round 5
// baseline (198.330 us; speedup 1.0000x reference)
//
#include <hip/hip_runtime.h>
#include <hip/hip_bf16.h>

// ---- problem constants ----
constexpr int BATCH = 256;          // B
constexpr int MTOK  = 128;          // tokens per text
constexpr int DDIM  = 768;          // embedding dim
constexpr int NV    = BATCH * DDIM; // v_final elems
constexpr float INV_TEMP = 1.0f / 0.07f;

typedef __bf16 bf16;
typedef __bf16 bf16x4 __attribute__((ext_vector_type(4)));
typedef __bf16 bf16x8 __attribute__((ext_vector_type(8)));
typedef float  f32x4  __attribute__((ext_vector_type(4)));

// ============================================================
// Kernel 0: V fp32 -> bf16 (768 KB -> 384 KB, L2-resident afterwards)
// ============================================================
__global__ __launch_bounds__(256) void convert_v_kernel(
        const float4* __restrict__ v4, bf16x4* __restrict__ out) {
    int i = blockIdx.x * 256 + threadIdx.x;
    if (i >= NV / 4) return;
    float4 f = v4[i];
    bf16x4 o;
    o.x = (bf16)f.x; o.y = (bf16)f.y; o.z = (bf16)f.z; o.w = (bf16)f.w;
    out[i] = o;
}

// ============================================================
// Kernel 1 (v5): BARRIER-FREE K-loop, no LDS staging.
// Block (j, nh): M=256 x N=64 tokens. 4 waves = 4 M-stripes of 64.
// Per wave 64x64 tile, acc 4x4 f32x4.
//   A: bf16x8 frag loads straight from L2-resident Vb (no LDS round-trip).
//   B: fp32 float4-pair loads from HBM, cvt->bf16 in regs (4-way wave
//      redundancy served by L2 multicast).
// One-h-step (K=32) register prefetch on both operands; the only
// __syncthreads is in the tiny epilogue. Compiler is free to keep B's
// HBM loads in flight across K-iterations (no barrier drain).
// ============================================================
__global__ __launch_bounds__(256, 2) void gemm_max_kernel(
        const bf16*  __restrict__ Vb,  // [256][768] bf16
        const float* __restrict__ T,   // [32768][768] fp32
        float* __restrict__ Sp) {      // [2][256][256]  Sp[nh][j][i]
    __shared__ float smax[256];

    const int jt   = blockIdx.x >> 1;   // text j
    const int nh   = blockIdx.x & 1;    // token half (64 tokens)
    const int tid  = threadIdx.x;
    const int w    = tid >> 6;          // wave 0..3 -> M stripe
    const int lane = tid & 63;
    const int quad = lane >> 4;
    const int l15  = lane & 15;

    // frag base pointers (K-invariant part)
    // A frag (m-tile t): row = w*64 + t*16 + l15, k-base = quad*8
    const bf16* aptr[4];
    // B frag (n-tile t): token row = nh*64 + t*16 + l15, k-base = quad*8
    const float* bptr[4];
#pragma unroll
    for (int t = 0; t < 4; ++t) {
        aptr[t] = Vb + (size_t)(w * 64 + t * 16 + l15) * DDIM + quad * 8;
        bptr[t] = T + (size_t)(jt * MTOK + nh * 64 + t * 16 + l15) * DDIM + quad * 8;
    }

    f32x4 acc[4][4] = {};

    // prefetch h-step 0 (k-offset 0)
    bf16x8 apre[4];
    float4 bpre[4][2];
#pragma unroll
    for (int t = 0; t < 4; ++t) {
        apre[t]    = *(const bf16x8*)(aptr[t]);
        bpre[t][0] = *(const float4*)(bptr[t]);
        bpre[t][1] = *(const float4*)(bptr[t] + 4);
    }

    // 24 h-steps of K=32 (DDIM = 768)
    for (int s = 0; s < 24; ++s) {
        bf16x8 af[4], bb[4];
#pragma unroll
        for (int t = 0; t < 4; ++t) {
            af[t] = apre[t];
            bb[t][0] = (bf16)bpre[t][0].x; bb[t][1] = (bf16)bpre[t][0].y;
            bb[t][2] = (bf16)bpre[t][0].z; bb[t][3] = (bf16)bpre[t][0].w;
            bb[t][4] = (bf16)bpre[t][1].x; bb[t][5] = (bf16)bpre[t][1].y;
            bb[t][6] = (bf16)bpre[t][1].z; bb[t][7] = (bf16)bpre[t][1].w;
        }
        if (s < 23) {
            const int ko = (s + 1) * 32;
#pragma unroll
            for (int t = 0; t < 4; ++t) {
                apre[t]    = *(const bf16x8*)(aptr[t] + ko);
                bpre[t][0] = *(const float4*)(bptr[t] + ko);
                bpre[t][1] = *(const float4*)(bptr[t] + ko + 4);
            }
        }
#pragma unroll
        for (int tr = 0; tr < 4; ++tr)
#pragma unroll
            for (int tc = 0; tc < 4; ++tc)
                acc[tr][tc] = __builtin_amdgcn_mfma_f32_16x16x32_bf16(
                    af[tr], bb[tc], acc[tr][tc], 0, 0, 0);
    }

    // epilogue: max over this half's 64 tokens (cols = tc*16 + l15)
    // C/D layout: col = lane&15, row = quad*4 + reg   [m89/m91]
#pragma unroll
    for (int tr = 0; tr < 4; ++tr) {
#pragma unroll
        for (int r = 0; r < 4; ++r) {
            float v = acc[tr][0][r];
            v = fmaxf(v, acc[tr][1][r]);
            v = fmaxf(v, acc[tr][2][r]);
            v = fmaxf(v, acc[tr][3][r]);
            v = fmaxf(v, __shfl_xor(v, 1, 64));
            v = fmaxf(v, __shfl_xor(v, 2, 64));
            v = fmaxf(v, __shfl_xor(v, 4, 64));
            v = fmaxf(v, __shfl_xor(v, 8, 64));
            if (l15 == 0)
                smax[w * 64 + tr * 16 + quad * 4 + r] = v;
        }
    }
    __syncthreads();
    Sp[(size_t)nh * BATCH * BATCH + (size_t)jt * BATCH + tid] = smax[tid] * INV_TEMP;
}

// ============================================================
// CE stage 1: block t (256 blocks x 1 wave) computes
//   partial[t] = 0.5*(lse_j S[t][j] + lse_i S[i][t]) - S[t][t]
// where S[i][j] = max(Sp[0][j][i], Sp[1][j][i]).
// ============================================================
__global__ __launch_bounds__(64) void ce1_kernel(
        const float* __restrict__ Sp, float* __restrict__ partial) {
    const int t = blockIdx.x;
    const int l = threadIdx.x;
    const float* Sp0 = Sp;
    const float* Sp1 = Sp + BATCH * BATCH;

    float vr[4], vc[4];
#pragma unroll
    for (int p = 0; p < 4; ++p) {
        int j = p * 64 + l;
        vr[p] = fmaxf(Sp0[j * BATCH + t], Sp1[j * BATCH + t]);  // S[t][j]
        int i = p * 64 + l;
        vc[p] = fmaxf(Sp0[t * BATCH + i], Sp1[t * BATCH + i]);  // S[i][t]
    }
    float mr = fmaxf(fmaxf(vr[0], vr[1]), fmaxf(vr[2], vr[3]));
    float mc = fmaxf(fmaxf(vc[0], vc[1]), fmaxf(vc[2], vc[3]));
    for (int o = 32; o > 0; o >>= 1) {
        mr = fmaxf(mr, __shfl_xor(mr, o, 64));
        mc = fmaxf(mc, __shfl_xor(mc, o, 64));
    }
    float sr = 0.f, sc = 0.f;
#pragma unroll
    for (int p = 0; p < 4; ++p) {
        sr += expf(vr[p] - mr);
        sc += expf(vc[p] - mc);
    }
    for (int o = 32; o > 0; o >>= 1) {
        sr += __shfl_xor(sr, o, 64);
        sc += __shfl_xor(sc, o, 64);
    }
    if (l == 0) {
        float diag = fmaxf(Sp0[t * BATCH + t], Sp1[t * BATCH + t]);
        partial[t] = 0.5f * ((mr + logf(sr)) + (mc + logf(sc))) - diag;
    }
}

// ============================================================
// CE stage 2: mean of 256 partials
// ============================================================
__global__ __launch_bounds__(256) void ce2_kernel(
        const float* __restrict__ partial, float* __restrict__ out) {
    const int i = threadIdx.x;
    float term = partial[i];
    for (int o = 32; o > 0; o >>= 1) term += __shfl_down(term, o, 64);
    __shared__ float ps[4];
    if ((i & 63) == 0) ps[i >> 6] = term;
    __syncthreads();
    if (i == 0) out[0] = (ps[0] + ps[1] + ps[2] + ps[3]) / (float)BATCH;
}

// ============================================================
extern "C" void kernel_launch(void* const* d_in, const int* in_sizes, int n_in,
                              void* d_out, int out_size, void* d_ws, size_t ws_size,
                              hipStream_t stream) {
    const float* v = (const float*)d_in[0];   // [256][768] fp32
    const float* T = (const float*)d_in[1];   // [256][128][768] fp32

    // ws: [ Vb bf16 NV | Sp f32 2*256*256 | partial f32 256 ]
    bf16*  Vb = (bf16*)d_ws;
    float* Sp = (float*)((char*)d_ws + (size_t)NV * sizeof(bf16));
    float* partial = Sp + 2 * BATCH * BATCH;

    convert_v_kernel<<<(NV / 4 + 255) / 256, 256, 0, stream>>>(
        (const float4*)v, (bf16x4*)Vb);
    gemm_max_kernel<<<512, 256, 0, stream>>>(Vb, T, Sp);
    ce1_kernel<<<256, 64, 0, stream>>>(Sp, partial);
    ce2_kernel<<<1, 256, 0, stream>>>(partial, (float*)d_out);
}

// Round 6
// 171.554 us; speedup vs baseline: 1.1561x; 1.1561x over previous
//
#include <hip/hip_runtime.h>
#include <hip/hip_bf16.h>

// ---- problem constants ----
constexpr int BATCH = 256;          // B
constexpr int MTOK  = 128;          // tokens per text
constexpr int DDIM  = 768;          // embedding dim
constexpr int NV    = BATCH * DDIM; // v elems (= Vq elems)
constexpr float INV_TEMP = 1.0f / 0.07f;

typedef __bf16 bf16;
typedef __bf16 bf16x8 __attribute__((ext_vector_type(8)));
typedef float  f32x4  __attribute__((ext_vector_type(4)));

// ============================================================
// Kernel 0: pack V fp32 -> bf16 in MFMA A-fragment layout.
// Vq[g][ks][lane] : g = 16-row M-tile (0..15), ks = K-step of 32 (0..23),
// lane = quad*16+l15 (0..63), each lane chunk = 8 bf16 = rows g*16+l15,
// k = ks*32 + quad*8 .. +8.  One frag = 64 lanes x 16 B = 1 KB contiguous
// -> A-frag load in the GEMM is a single fully-coalesced dwordx4.
// ============================================================
__global__ __launch_bounds__(256) void pack_v_kernel(
        const float* __restrict__ V, bf16x8* __restrict__ Vq) {
    int c = blockIdx.x * 256 + threadIdx.x;        // chunk id, 24576 total
    int lane = c & 63, fs = c >> 6;
    int ks = fs % 24, g = fs / 24;
    int l15 = lane & 15, quad = lane >> 4;
    const float* src = V + (size_t)(g * 16 + l15) * DDIM + ks * 32 + quad * 8;
    float4 f0 = *(const float4*)(src);
    float4 f1 = *(const float4*)(src + 4);
    bf16x8 o;
    o[0] = (bf16)f0.x; o[1] = (bf16)f0.y; o[2] = (bf16)f0.z; o[3] = (bf16)f0.w;
    o[4] = (bf16)f1.x; o[5] = (bf16)f1.y; o[6] = (bf16)f1.z; o[7] = (bf16)f1.w;
    Vq[c] = o;                                      // coalesced write
}

// ============================================================
// Kernel 1 (v6): block (j, nh) -> M=256 x N=32 tokens, BK=64, 12 iters.
// A: direct coalesced frag loads from L2-resident Vq (no LDS, no barrier dep).
// B: fp32 -> regs -> bf16 -> LDS, DOUBLE-BUFFERED, ONE barrier per iter.
// LDS ~9.2 KB, VGPR<=128 -> 4 blocks/CU (16 waves) hide drains/latency.
// ============================================================
__global__ __launch_bounds__(256, 4) void gemm_max_kernel(
        const bf16*  __restrict__ Vq,  // packed A frags
        const float* __restrict__ T,   // [32768][768] fp32
        float* __restrict__ Sp) {      // [4][256][256]  Sp[nh][j][i]
    // B buf: 2 khalf x 32 rows x 64 B = 4096 B; two bufs.
    __shared__ char  ldsB[2 * 4096];
    __shared__ float smax[256];

    const int jt   = blockIdx.x >> 2;   // text j
    const int nh   = blockIdx.x & 3;    // token quarter (32 tokens)
    const int tid  = threadIdx.x;
    const int w    = tid >> 6;          // wave 0..3 -> M stripe
    const int lane = tid & 63;
    const int quad = lane >> 4;
    const int l15  = lane & 15;

    // --- A frag bases: m-tile t -> global 16-row tile g = w*4+t ---
    const bf16* aBase[4];
#pragma unroll
    for (int t = 0; t < 4; ++t)
        aBase[t] = Vq + ((size_t)(w * 4 + t) * 24) * 512 + lane * 8;

    // --- B staging: thread -> (row = tid>>3, kp = tid&7), 8 fp32/iter ---
    const int brow = tid >> 3, bkp = tid & 7;
    const float* gB = T + (size_t)(jt * MTOK + nh * 32 + brow) * DDIM + bkp * 8;
    const int bwoff = (bkp >> 2) * 2048 + brow * 64 + (((bkp & 3) ^ (brow & 3)) << 4);

    // --- B frag read offsets (buf term added in loop) ---
    int boff[2][2];
#pragma unroll
    for (int h = 0; h < 2; ++h)
#pragma unroll
        for (int tc = 0; tc < 2; ++tc) {
            int br = tc * 16 + l15;
            boff[h][tc] = h * 2048 + br * 64 + ((quad ^ (l15 & 3)) << 4);
        }

    f32x4 acc[4][2] = {};

    auto cvt_store = [&](float4 a, float4 b, int bufo) {
        bf16x8 o;
        o[0] = (bf16)a.x; o[1] = (bf16)a.y; o[2] = (bf16)a.z; o[3] = (bf16)a.w;
        o[4] = (bf16)b.x; o[5] = (bf16)b.y; o[6] = (bf16)b.z; o[7] = (bf16)b.w;
        *(bf16x8*)(ldsB + bufo + bwoff) = o;
    };

    // prologue: slab0 -> buf0; slab1 -> regs
    {
        float4 r0 = *(const float4*)(gB);
        float4 r1 = *(const float4*)(gB + 4);
        cvt_store(r0, r1, 0);
    }
    float4 breg0 = *(const float4*)(gB + 64);
    float4 breg1 = *(const float4*)(gB + 64 + 4);
    bf16x8 apre[4];
#pragma unroll
    for (int t = 0; t < 4; ++t) apre[t] = *(const bf16x8*)(aBase[t]);
    __syncthreads();

    for (int kk = 0; kk < 12; ++kk) {
        const int buf  = (kk & 1) * 4096;
        const int nbuf = buf ^ 4096;
        if (kk < 11) cvt_store(breg0, breg1, nbuf);   // stage slab kk+1
        if (kk < 10) {                                // fetch slab kk+2
            const float* p = gB + (kk + 2) * 64;
            breg0 = *(const float4*)(p);
            breg1 = *(const float4*)(p + 4);
        }
#pragma unroll
        for (int h = 0; h < 2; ++h) {
            const int hs = kk * 2 + h;
            bf16x8 af[4], bb[2];
#pragma unroll
            for (int t = 0; t < 4; ++t) af[t] = apre[t];
            if (hs < 23) {
#pragma unroll
                for (int t = 0; t < 4; ++t)
                    apre[t] = *(const bf16x8*)(aBase[t] + (size_t)(hs + 1) * 512);
            }
#pragma unroll
            for (int tc = 0; tc < 2; ++tc)
                bb[tc] = *(const bf16x8*)(ldsB + buf + boff[h][tc]);
#pragma unroll
            for (int tr = 0; tr < 4; ++tr)
#pragma unroll
                for (int tc = 0; tc < 2; ++tc)
                    acc[tr][tc] = __builtin_amdgcn_mfma_f32_16x16x32_bf16(
                        af[tr], bb[tc], acc[tr][tc], 0, 0, 0);
        }
        __syncthreads();   // buf^1 writes visible; buf reads done
    }

    // epilogue: max over this quarter's 32 tokens (cols = tc*16 + l15)
    // C/D layout: col = lane&15, row = quad*4 + reg   [m89/m91]
#pragma unroll
    for (int tr = 0; tr < 4; ++tr) {
#pragma unroll
        for (int r = 0; r < 4; ++r) {
            float v = fmaxf(acc[tr][0][r], acc[tr][1][r]);
            v = fmaxf(v, __shfl_xor(v, 1, 64));
            v = fmaxf(v, __shfl_xor(v, 2, 64));
            v = fmaxf(v, __shfl_xor(v, 4, 64));
            v = fmaxf(v, __shfl_xor(v, 8, 64));
            if (l15 == 0)
                smax[w * 64 + tr * 16 + quad * 4 + r] = v;
        }
    }
    __syncthreads();
    Sp[((size_t)nh * BATCH + jt) * BATCH + tid] = smax[tid] * INV_TEMP;
}

// ============================================================
// CE stage 1: block t computes
//   partial[t] = 0.5*(lse_j S[t][j] + lse_i S[i][t]) - S[t][t]
// where S[i][j] = max_nh Sp[nh][j][i].
// ============================================================
__global__ __launch_bounds__(64) void ce1_kernel(
        const float* __restrict__ Sp, float* __restrict__ partial) {
    const int t = blockIdx.x;
    const int l = threadIdx.x;
    const int P = BATCH * BATCH;

    float vr[4], vc[4];
#pragma unroll
    for (int p = 0; p < 4; ++p) {
        int j = p * 64 + l;
        float a = fmaxf(Sp[0 * P + j * BATCH + t], Sp[1 * P + j * BATCH + t]);
        float b = fmaxf(Sp[2 * P + j * BATCH + t], Sp[3 * P + j * BATCH + t]);
        vr[p] = fmaxf(a, b);                                    // S[t][j]
        int i = p * 64 + l;
        float c = fmaxf(Sp[0 * P + t * BATCH + i], Sp[1 * P + t * BATCH + i]);
        float d = fmaxf(Sp[2 * P + t * BATCH + i], Sp[3 * P + t * BATCH + i]);
        vc[p] = fmaxf(c, d);                                    // S[i][t]
    }
    float mr = fmaxf(fmaxf(vr[0], vr[1]), fmaxf(vr[2], vr[3]));
    float mc = fmaxf(fmaxf(vc[0], vc[1]), fmaxf(vc[2], vc[3]));
    for (int o = 32; o > 0; o >>= 1) {
        mr = fmaxf(mr, __shfl_xor(mr, o, 64));
        mc = fmaxf(mc, __shfl_xor(mc, o, 64));
    }
    float sr = 0.f, sc = 0.f;
#pragma unroll
    for (int p = 0; p < 4; ++p) {
        sr += expf(vr[p] - mr);
        sc += expf(vc[p] - mc);
    }
    for (int o = 32; o > 0; o >>= 1) {
        sr += __shfl_xor(sr, o, 64);
        sc += __shfl_xor(sc, o, 64);
    }
    if (l == 0) {
        float d0 = fmaxf(Sp[0 * P + t * BATCH + t], Sp[1 * P + t * BATCH + t]);
        float d1 = fmaxf(Sp[2 * P + t * BATCH + t], Sp[3 * P + t * BATCH + t]);
        partial[t] = 0.5f * ((mr + logf(sr)) + (mc + logf(sc))) - fmaxf(d0, d1);
    }
}

// ============================================================
// CE stage 2: mean of 256 partials
// ============================================================
__global__ __launch_bounds__(256) void ce2_kernel(
        const float* __restrict__ partial, float* __restrict__ out) {
    const int i = threadIdx.x;
    float term = partial[i];
    for (int o = 32; o > 0; o >>= 1) term += __shfl_down(term, o, 64);
    __shared__ float ps[4];
    if ((i & 63) == 0) ps[i >> 6] = term;
    __syncthreads();
    if (i == 0) out[0] = (ps[0] + ps[1] + ps[2] + ps[3]) / (float)BATCH;
}

// ============================================================
extern "C" void kernel_launch(void* const* d_in, const int* in_sizes, int n_in,
                              void* d_out, int out_size, void* d_ws, size_t ws_size,
                              hipStream_t stream) {
    const float* v = (const float*)d_in[0];   // [256][768] fp32
    const float* T = (const float*)d_in[1];   // [256][128][768] fp32

    // ws: [ Vq bf16 NV | Sp f32 4*256*256 | partial f32 256 ]
    bf16*  Vq = (bf16*)d_ws;
    float* Sp = (float*)((char*)d_ws + (size_t)NV * sizeof(bf16));
    float* partial = Sp + 4 * BATCH * BATCH;

    pack_v_kernel<<<96, 256, 0, stream>>>(v, (bf16x8*)Vq);
    gemm_max_kernel<<<1024, 256, 0, stream>>>(Vq, T, Sp);
    ce1_kernel<<<256, 64, 0, stream>>>(Sp, partial);
    ce2_kernel<<<1, 256, 0, stream>>>(partial, (float*)d_out);
}

// Round 7
// 163.469 us; speedup vs baseline: 1.2133x; 1.0495x over previous
//
#include <hip/hip_runtime.h>
#include <hip/hip_bf16.h>

// ---- problem constants ----
constexpr int BATCH = 256;          // B
constexpr int MTOK  = 128;          // tokens per text
constexpr int DDIM  = 768;          // embedding dim
constexpr int NV    = BATCH * DDIM; // v elems (= Vq elems)
constexpr float INV_TEMP = 1.0f / 0.07f;

typedef __bf16 bf16;
typedef __bf16 bf16x8 __attribute__((ext_vector_type(8)));
typedef float  f32x4  __attribute__((ext_vector_type(4)));

// ============================================================
// Kernel 0: pack V fp32 -> bf16 in MFMA A-fragment layout.
// Vq chunk c = (g*24 + ks)*64 + lane ; lane chunk = 8 bf16 covering
// rows g*16+l15, k = ks*32 + quad*8.. +8.  One frag = 1 KB contiguous.
// ============================================================
__global__ __launch_bounds__(256) void pack_v_kernel(
        const float* __restrict__ V, bf16x8* __restrict__ Vq) {
    int c = blockIdx.x * 256 + threadIdx.x;        // 24576 chunks
    int lane = c & 63, fs = c >> 6;
    int ks = fs % 24, g = fs / 24;
    int l15 = lane & 15, quad = lane >> 4;
    const float* src = V + (size_t)(g * 16 + l15) * DDIM + ks * 32 + quad * 8;
    float4 f0 = *(const float4*)(src);
    float4 f1 = *(const float4*)(src + 4);
    bf16x8 o;
    o[0] = (bf16)f0.x; o[1] = (bf16)f0.y; o[2] = (bf16)f0.z; o[3] = (bf16)f0.w;
    o[4] = (bf16)f1.x; o[5] = (bf16)f1.y; o[6] = (bf16)f1.z; o[7] = (bf16)f1.w;
    Vq[c] = o;
}

// ============================================================
// Kernel 1 (v7): block (j, nh) -> M=256 x N=64 tokens, BK=64, 12 iters.
// A: direct coalesced frag loads from L2-resident Vq, prefetch DEPTH-2
//    (issued one full h-step ahead -> L2 latency hidden, barrier drain ~0).
// B: fp32 -> regs -> bf16 -> LDS, double-buffered, ONE barrier per iter.
// Grid 512, 256 thr -> 2 blocks/CU; ~150 VGPR.
// ============================================================
__global__ __launch_bounds__(256, 2) void gemm_max_kernel(
        const bf16*  __restrict__ Vq,  // packed A frags
        const float* __restrict__ T,   // [32768][768] fp32
        float* __restrict__ Sp) {      // [2][256][256]  Sp[nh][j][i]
    // B buf: 2 khalf x 64 rows x 64 B = 8192 B; two bufs.
    __shared__ char  ldsB[2 * 8192];
    __shared__ float smax[256];

    const int jt   = blockIdx.x >> 1;   // text j
    const int nh   = blockIdx.x & 1;    // token half (64 tokens)
    const int tid  = threadIdx.x;
    const int w    = tid >> 6;          // wave 0..3 -> M stripe of 64
    const int lane = tid & 63;
    const int quad = lane >> 4;
    const int l15  = lane & 15;

    // --- A frag bases: m-tile t -> 16-row tile g = w*4+t ---
    const bf16* aBase[4];
#pragma unroll
    for (int t = 0; t < 4; ++t)
        aBase[t] = Vq + ((size_t)(w * 4 + t) * 24) * 512 + lane * 8;

    // --- B staging: chunk c = q*256+tid -> row = c>>3 (0..63), kp = c&7 ---
    const float* gB[2];
    int bwoff[2];
#pragma unroll
    for (int q = 0; q < 2; ++q) {
        int c = q * 256 + tid;
        int row = c >> 3, kp = c & 7;
        gB[q] = T + (size_t)(jt * MTOK + nh * 64 + row) * DDIM + kp * 8;
        bwoff[q] = (kp >> 2) * 4096 + row * 64 + ((kp & 3) << 4);
    }

    // --- B frag read offsets ---
    int boff[2][4];
#pragma unroll
    for (int h = 0; h < 2; ++h)
#pragma unroll
        for (int tc = 0; tc < 4; ++tc)
            boff[h][tc] = h * 4096 + (tc * 16 + l15) * 64 + quad * 16;

    f32x4 acc[4][4] = {};

    auto cvt_store = [&](float4 a, float4 b, int q, int bufo) {
        bf16x8 o;
        o[0] = (bf16)a.x; o[1] = (bf16)a.y; o[2] = (bf16)a.z; o[3] = (bf16)a.w;
        o[4] = (bf16)b.x; o[5] = (bf16)b.y; o[6] = (bf16)b.z; o[7] = (bf16)b.w;
        *(bf16x8*)(ldsB + bufo + bwoff[q]) = o;
    };

    // prologue: slab0 -> buf0; slab1 -> regs; A frags hs=0,1 -> regs
    float4 breg[2][2];
#pragma unroll
    for (int q = 0; q < 2; ++q) {
        float4 r0 = *(const float4*)(gB[q]);
        float4 r1 = *(const float4*)(gB[q] + 4);
        cvt_store(r0, r1, q, 0);
        breg[q][0] = *(const float4*)(gB[q] + 64);
        breg[q][1] = *(const float4*)(gB[q] + 64 + 4);
    }
    bf16x8 apre[2][4];
#pragma unroll
    for (int h = 0; h < 2; ++h)
#pragma unroll
        for (int t = 0; t < 4; ++t)
            apre[h][t] = *(const bf16x8*)(aBase[t] + (size_t)h * 512);
    __syncthreads();

    for (int kk = 0; kk < 12; ++kk) {
        const int buf  = (kk & 1) * 8192;
        const int nbuf = buf ^ 8192;
        if (kk < 11) {                       // stage slab kk+1 (regs -> LDS)
#pragma unroll
            for (int q = 0; q < 2; ++q)
                cvt_store(breg[q][0], breg[q][1], q, nbuf);
        }
        if (kk < 10) {                       // fetch slab kk+2 -> regs
#pragma unroll
            for (int q = 0; q < 2; ++q) {
                const float* p = gB[q] + (kk + 2) * 64;
                breg[q][0] = *(const float4*)(p);
                breg[q][1] = *(const float4*)(p + 4);
            }
        }
#pragma unroll
        for (int h = 0; h < 2; ++h) {
            const int hs = kk * 2 + h;
            bf16x8 af[4], bb[4];
#pragma unroll
            for (int t = 0; t < 4; ++t) af[t] = apre[h][t];
            if (hs + 2 < 24) {               // depth-2 A prefetch
#pragma unroll
                for (int t = 0; t < 4; ++t)
                    apre[h][t] = *(const bf16x8*)(aBase[t] + (size_t)(hs + 2) * 512);
            }
#pragma unroll
            for (int tc = 0; tc < 4; ++tc)
                bb[tc] = *(const bf16x8*)(ldsB + buf + boff[h][tc]);
#pragma unroll
            for (int tr = 0; tr < 4; ++tr)
#pragma unroll
                for (int tc = 0; tc < 4; ++tc)
                    acc[tr][tc] = __builtin_amdgcn_mfma_f32_16x16x32_bf16(
                        af[tr], bb[tc], acc[tr][tc], 0, 0, 0);
        }
        __syncthreads();   // prev readers of nbuf done; buf writes visible
    }

    // epilogue: max over this half's 64 tokens (cols = tc*16 + l15)
    // C/D layout: col = lane&15, row = quad*4 + reg   [m89/m91]
#pragma unroll
    for (int tr = 0; tr < 4; ++tr) {
#pragma unroll
        for (int r = 0; r < 4; ++r) {
            float v = fmaxf(fmaxf(acc[tr][0][r], acc[tr][1][r]),
                            fmaxf(acc[tr][2][r], acc[tr][3][r]));
            v = fmaxf(v, __shfl_xor(v, 1, 64));
            v = fmaxf(v, __shfl_xor(v, 2, 64));
            v = fmaxf(v, __shfl_xor(v, 4, 64));
            v = fmaxf(v, __shfl_xor(v, 8, 64));
            if (l15 == 0)
                smax[w * 64 + tr * 16 + quad * 4 + r] = v;
        }
    }
    __syncthreads();
    Sp[((size_t)nh * BATCH + jt) * BATCH + tid] = smax[tid] * INV_TEMP;
}

// ============================================================
// CE stage 1: block t computes
//   partial[t] = 0.5*(lse_j S[t][j] + lse_i S[i][t]) - S[t][t]
// where S[i][j] = max(Sp[0][j][i], Sp[1][j][i]).
// ============================================================
__global__ __launch_bounds__(64) void ce1_kernel(
        const float* __restrict__ Sp, float* __restrict__ partial) {
    const int t = blockIdx.x;
    const int l = threadIdx.x;
    const float* Sp0 = Sp;
    const float* Sp1 = Sp + BATCH * BATCH;

    float vr[4], vc[4];
#pragma unroll
    for (int p = 0; p < 4; ++p) {
        int j = p * 64 + l;
        vr[p] = fmaxf(Sp0[j * BATCH + t], Sp1[j * BATCH + t]);  // S[t][j]
        int i = p * 64 + l;
        vc[p] = fmaxf(Sp0[t * BATCH + i], Sp1[t * BATCH + i]);  // S[i][t]
    }
    float mr = fmaxf(fmaxf(vr[0], vr[1]), fmaxf(vr[2], vr[3]));
    float mc = fmaxf(fmaxf(vc[0], vc[1]), fmaxf(vc[2], vc[3]));
    for (int o = 32; o > 0; o >>= 1) {
        mr = fmaxf(mr, __shfl_xor(mr, o, 64));
        mc = fmaxf(mc, __shfl_xor(mc, o, 64));
    }
    float sr = 0.f, sc = 0.f;
#pragma unroll
    for (int p = 0; p < 4; ++p) {
        sr += expf(vr[p] - mr);
        sc += expf(vc[p] - mc);
    }
    for (int o = 32; o > 0; o >>= 1) {
        sr += __shfl_xor(sr, o, 64);
        sc += __shfl_xor(sc, o, 64);
    }
    if (l == 0) {
        float diag = fmaxf(Sp0[t * BATCH + t], Sp1[t * BATCH + t]);
        partial[t] = 0.5f * ((mr + logf(sr)) + (mc + logf(sc))) - diag;
    }
}

// ============================================================
// CE stage 2: mean of 256 partials
// ============================================================
__global__ __launch_bounds__(256) void ce2_kernel(
        const float* __restrict__ partial, float* __restrict__ out) {
    const int i = threadIdx.x;
    float term = partial[i];
    for (int o = 32; o > 0; o >>= 1) term += __shfl_down(term, o, 64);
    __shared__ float ps[4];
    if ((i & 63) == 0) ps[i >> 6] = term;
    __syncthreads();
    if (i == 0) out[0] = (ps[0] + ps[1] + ps[2] + ps[3]) / (float)BATCH;
}

// ============================================================
extern "C" void kernel_launch(void* const* d_in, const int* in_sizes, int n_in,
                              void* d_out, int out_size, void* d_ws, size_t ws_size,
                              hipStream_t stream) {
    const float* v = (const float*)d_in[0];   // [256][768] fp32
    const float* T = (const float*)d_in[1];   // [256][128][768] fp32

    // ws: [ Vq bf16 NV | Sp f32 2*256*256 | partial f32 256 ]
    bf16*  Vq = (bf16*)d_ws;
    float* Sp = (float*)((char*)d_ws + (size_t)NV * sizeof(bf16));
    float* partial = Sp + 2 * BATCH * BATCH;

    pack_v_kernel<<<96, 256, 0, stream>>>(v, (bf16x8*)Vq);
    gemm_max_kernel<<<512, 256, 0, stream>>>(Vq, T, Sp);
    ce1_kernel<<<256, 64, 0, stream>>>(Sp, partial);
    ce2_kernel<<<1, 256, 0, stream>>>(partial, (float*)d_out);
}